// Round 10
// baseline (306.440 us; speedup 1.0000x reference)
//
#include <hip/hip_runtime.h>
#include <hip/hip_fp16.h>
#include <math.h>

#define SS 2048
#define DD 512
#define NH 8
#define HD 64

typedef __attribute__((ext_vector_type(8))) short frag_ab;   // 8 fp16
typedef __attribute__((ext_vector_type(4))) float frag_cd;   // 4 fp32

static __device__ inline unsigned int pack_h2(float x, float y) {
    __half2 t = __floats2half2_rn(x, y);   // x -> low half
    return *(unsigned int*)&t;
}

// ---------- GEMM: q_h = fp16(x @ Wq); B transposed in-register during staging ----------
__global__ __launch_bounds__(256, 4) void gemm_kernel(const float* __restrict__ x,
                                                      const float* __restrict__ w,
                                                      unsigned short* __restrict__ q) {
    __shared__ __align__(16) unsigned short Ah[2][64 * 72];  // [m][k]
    __shared__ __align__(16) unsigned short Bt[2][64 * 72];  // [n][k]
    const int tid = threadIdx.x;
    const int lane = tid & 63, wv = tid >> 6;
    const int a = lane & 15, g = lane >> 4;
    const int bm = blockIdx.x, bn = blockIdx.y;

    frag_cd acc[4] = {};
    const int asr = tid >> 4;
    const int ac4 = (tid & 15) * 4;
    const int bnn = (tid & 31) * 2;
    const int bkk = (tid >> 5) * 8;

    float4 av[4];
    float2 bv[8];
    #pragma unroll
    for (int p = 0; p < 4; ++p)
        av[p] = *(const float4*)(x + (size_t)(bm * 64 + asr + p * 16) * 512 + ac4);
    #pragma unroll
    for (int j = 0; j < 8; ++j)
        bv[j] = *(const float2*)(w + (size_t)(bkk + j) * 512 + bn * 64 + bnn);

    for (int it = 0; it < 8; ++it) {
        const int cur = it & 1;
        #pragma unroll
        for (int p = 0; p < 4; ++p) {
            uint2 hh = { pack_h2(av[p].x, av[p].y), pack_h2(av[p].z, av[p].w) };
            *(uint2*)&Ah[cur][(asr + p * 16) * 72 + ac4] = hh;
        }
        {
            unsigned int t0[4], t1[4];
            #pragma unroll
            for (int j = 0; j < 4; ++j) {
                t0[j] = pack_h2(bv[2 * j].x, bv[2 * j + 1].x);
                t1[j] = pack_h2(bv[2 * j].y, bv[2 * j + 1].y);
            }
            *(uint4*)&Bt[cur][bnn * 72 + bkk]       = *(uint4*)t0;
            *(uint4*)&Bt[cur][(bnn + 1) * 72 + bkk] = *(uint4*)t1;
        }
        __syncthreads();
        if (it < 7) {
            const int k0 = (it + 1) * 64;
            #pragma unroll
            for (int p = 0; p < 4; ++p)
                av[p] = *(const float4*)(x + (size_t)(bm * 64 + asr + p * 16) * 512 + k0 + ac4);
            #pragma unroll
            for (int j = 0; j < 8; ++j)
                bv[j] = *(const float2*)(w + (size_t)(k0 + bkk + j) * 512 + bn * 64 + bnn);
        }
        #pragma unroll
        for (int kh = 0; kh < 2; ++kh) {
            const frag_ab bf = *(const frag_ab*)&Bt[cur][(wv * 16 + a) * 72 + kh * 32 + g * 8];
            #pragma unroll
            for (int mt = 0; mt < 4; ++mt) {
                const frag_ab af = *(const frag_ab*)&Ah[cur][(mt * 16 + a) * 72 + kh * 32 + g * 8];
                acc[mt] = __builtin_amdgcn_mfma_f32_16x16x32_f16(af, bf, acc[mt], 0, 0, 0);
            }
        }
    }
    #pragma unroll
    for (int mt = 0; mt < 4; ++mt)
        #pragma unroll
        for (int r = 0; r < 4; ++r) {
            const int m = bm * 64 + mt * 16 + g * 4 + r;
            const int n = bn * 64 + wv * 16 + a;
            __half hv = __float2half_rn(acc[mt][r]);
            q[(size_t)m * 512 + n] = *(unsigned short*)&hv;
        }
}

// ---------- Flash attention: 8 waves = 4 q-quarters x 2 key-halves; P via ds_bpermute ----
// LDS tiles stride 64 shorts, 16B chunks XOR-swizzled by (row&7): K b32 staging writes
// 2-way free, V^T transposed uint4 writes uniform (R9's were 8-way), all b128 reads
// quad-uniform. P never touches LDS: C-layout -> B-layout via 16 bpermutes + selects.
// exp2 offset folded into MFMA C-init. No-max softmax, in-block kv combine.
__global__ __launch_bounds__(512, 6) void attn_kernel(const __half* __restrict__ qg,
                                                      float* __restrict__ out) {
    __shared__ __align__(16) char smem[34304];
    unsigned short* Kt = (unsigned short*)smem;            // [2][64 rows][64] swizzled, 16 KB
    unsigned short* Vt = (unsigned short*)smem + 8192;     // [2][64 rows][64] swizzled, 16 KB

    const int tid = threadIdx.x;
    const int lane = tid & 63, wv = tid >> 6;
    const int a = lane & 15, g = lane >> 4;
    const int a7 = a & 7;
    const int qq = wv & 3;            // q quarter (32 q)
    const int kv = wv >> 2;           // key half (1024 keys)
    const int bid = blockIdx.x;       // 512 = 16(qt) * 8(h) * 4(b)
    const int qt = bid & 15;
    const int h  = (bid >> 4) & 7;
    const int b  = bid >> 7;

    const unsigned short* qbh = (const unsigned short*)qg + (size_t)b * SS * DD + h * HD;
    const int qrow0 = qt * 128 + qq * 32;

    // Q B-fragments, pre-scaled by 0.125*log2(e)
    frag_ab qf[2][2];
    const __half2 qsc = __float2half2_rn(0.18033688011112042f);
    #pragma unroll
    for (int nt = 0; nt < 2; ++nt)
        #pragma unroll
        for (int kh = 0; kh < 2; ++kh) {
            frag_ab t = *(const frag_ab*)(qbh + (size_t)(qrow0 + nt * 16 + a) * DD + kh * 32 + g * 8);
            __half2* ph = (__half2*)&t;
            #pragma unroll
            for (int i = 0; i < 4; ++i) ph[i] = __hmul2(ph[i], qsc);
            qf[nt][kh] = t;
        }

    frag_cd oacc[4][2] = {};          // [ft][nt]
    float lsum[2] = {0.f, 0.f};

    // bpermute lane indices for the P transform
    const int pidx0 = ((lane & 15) + ((lane & 16) << 1)) << 2;   // a + 32*(g&1), bytes
    const int pidx1 = pidx0 + 64;
    const bool ghi = (lane >= 32);                               // g>>1

    // staging: threads 0-255 stage key-half 0, 256-511 half 1 (== own wave's kv)
    const int t8 = tid & 255;
    const int f0 = (t8 & 31) * 2;     // feature column (even)
    const int u8 = t8 >> 5;           // key chunk 0..7
    const int r0 = u8 * 8;
    const int keybase = (tid >> 8) * 1024;
    unsigned short* Ks = Kt + (tid >> 8) * 4096;
    unsigned short* Vs = Vt + (tid >> 8) * 4096;
    const int kc = f0 >> 3;           // K staging logical chunk
    const int ki = f0 & 7;            // K staging intra-chunk offset

    unsigned int d[8];
    #pragma unroll
    for (int k = 0; k < 8; ++k)
        d[k] = *(const unsigned int*)(qbh + (size_t)(keybase + r0 + k) * DD + f0);

    const unsigned short* Kc = Kt + kv * 4096;
    const unsigned short* Vc = Vt + kv * 4096;
    const float coff = -11.541560327111707f;   // -8*log2(e): p = 2^(s' + coff) = e^(s-8)

    for (int it = 0; it < 16; ++it) {
        __syncthreads();              // all waves done reading previous tiles
        #pragma unroll
        for (int k = 0; k < 8; ++k)   // K key-major, swizzled chunk (kc ^ k)
            *(unsigned int*)&Ks[(r0 + k) * 64 + ((kc ^ k) << 3) + ki] = d[k];
        {                             // V^T feature-major, swizzled chunk (u8 ^ (f&7))
            unsigned int vlo[4], vhi[4];
            #pragma unroll
            for (int j = 0; j < 4; ++j) {
                vlo[j] = (d[2 * j] & 0xFFFFu) | (d[2 * j + 1] << 16);
                vhi[j] = (d[2 * j] >> 16)     | (d[2 * j + 1] & 0xFFFF0000u);
            }
            *(uint4*)&Vs[f0 * 64 + ((u8 ^ (f0 & 7)) << 3)]             = *(uint4*)vlo;
            *(uint4*)&Vs[(f0 + 1) * 64 + ((u8 ^ ((f0 + 1) & 7)) << 3)] = *(uint4*)vhi;
        }
        __syncthreads();              // staged tiles visible

        if (it + 1 < 16) {            // prefetch next tile (overlaps compute)
            const int kb = keybase + (it + 1) * 64;
            #pragma unroll
            for (int k = 0; k < 8; ++k)
                d[k] = *(const unsigned int*)(qbh + (size_t)(kb + r0 + k) * DD + f0);
        }

        // ---- S^T = K . Q^T (C-init = exp offset), exp2, pack to u[] in registers ----
        unsigned int u[2][4][2];
        #pragma unroll
        for (int kt = 0; kt < 4; ++kt) {
            const frag_ab ka0 = *(const frag_ab*)&Kc[(kt * 16 + a) * 64 + ((g ^ a7) << 3)];
            const frag_ab ka1 = *(const frag_ab*)&Kc[(kt * 16 + a) * 64 + (((4 + g) ^ a7) << 3)];
            #pragma unroll
            for (int nt = 0; nt < 2; ++nt) {
                frag_cd c = {coff, coff, coff, coff};
                c = __builtin_amdgcn_mfma_f32_16x16x32_f16(ka0, qf[nt][0], c, 0, 0, 0);
                c = __builtin_amdgcn_mfma_f32_16x16x32_f16(ka1, qf[nt][1], c, 0, 0, 0);
                const float p0 = __builtin_amdgcn_exp2f(c[0]);
                const float p1 = __builtin_amdgcn_exp2f(c[1]);
                const float p2 = __builtin_amdgcn_exp2f(c[2]);
                const float p3 = __builtin_amdgcn_exp2f(c[3]);
                lsum[nt] += (p0 + p1) + (p2 + p3);
                u[nt][kt][0] = pack_h2(p0, p1);
                u[nt][kt][1] = pack_h2(p2, p3);
            }
        }
        // ---- O^T += V^T . P^T; P B-frags built in-register via ds_bpermute ----
        #pragma unroll
        for (int kh = 0; kh < 2; ++kh) {
            frag_ab pb[2];
            #pragma unroll
            for (int nt = 0; nt < 2; ++nt) {
                const int lo0 = __builtin_amdgcn_ds_bpermute(pidx0, (int)u[nt][2 * kh][0]);
                const int hi0 = __builtin_amdgcn_ds_bpermute(pidx0, (int)u[nt][2 * kh + 1][0]);
                const int lo1 = __builtin_amdgcn_ds_bpermute(pidx0, (int)u[nt][2 * kh][1]);
                const int hi1 = __builtin_amdgcn_ds_bpermute(pidx0, (int)u[nt][2 * kh + 1][1]);
                const int lo2 = __builtin_amdgcn_ds_bpermute(pidx1, (int)u[nt][2 * kh][0]);
                const int hi2 = __builtin_amdgcn_ds_bpermute(pidx1, (int)u[nt][2 * kh + 1][0]);
                const int lo3 = __builtin_amdgcn_ds_bpermute(pidx1, (int)u[nt][2 * kh][1]);
                const int hi3 = __builtin_amdgcn_ds_bpermute(pidx1, (int)u[nt][2 * kh + 1][1]);
                union { unsigned int w[4]; frag_ab f; } pu;
                pu.w[0] = (unsigned int)(ghi ? hi0 : lo0);
                pu.w[1] = (unsigned int)(ghi ? hi1 : lo1);
                pu.w[2] = (unsigned int)(ghi ? hi2 : lo2);
                pu.w[3] = (unsigned int)(ghi ? hi3 : lo3);
                pb[nt] = pu.f;
            }
            #pragma unroll
            for (int ft = 0; ft < 4; ++ft) {
                const frag_ab va = *(const frag_ab*)&Vc[(ft * 16 + a) * 64 + (((4 * kh + g) ^ a7) << 3)];
                oacc[ft][0] = __builtin_amdgcn_mfma_f32_16x16x32_f16(va, pb[0], oacc[ft][0], 0, 0, 0);
                oacc[ft][1] = __builtin_amdgcn_mfma_f32_16x16x32_f16(va, pb[1], oacc[ft][1], 0, 0, 0);
            }
        }
    }

    // ---- in-block combine: kv=1 -> LDS; kv=0 adds, normalizes, writes ----
    #pragma unroll
    for (int nt = 0; nt < 2; ++nt) {
        lsum[nt] += __shfl_xor(lsum[nt], 16, 64);
        lsum[nt] += __shfl_xor(lsum[nt], 32, 64);
    }
    __syncthreads();                              // all tile reads done; LDS reusable
    float* Obuf = (float*)smem;                   // [qq][f 64][q 32+1 pad] = 33792 B
    float* Lbuf = (float*)(smem + 33792);         // [qq][q 32]
    if (kv == 1) {
        #pragma unroll
        for (int ft = 0; ft < 4; ++ft)
            #pragma unroll
            for (int nt = 0; nt < 2; ++nt)
                #pragma unroll
                for (int r = 0; r < 4; ++r)
                    Obuf[qq * 2112 + (ft * 16 + g * 4 + r) * 33 + nt * 16 + a] = oacc[ft][nt][r];
        if (g == 0)
            #pragma unroll
            for (int nt = 0; nt < 2; ++nt)
                Lbuf[qq * 32 + nt * 16 + a] = lsum[nt];
    }
    __syncthreads();
    if (kv == 0) {
        #pragma unroll
        for (int nt = 0; nt < 2; ++nt) {
            const float inv = 1.f / (lsum[nt] + Lbuf[qq * 32 + nt * 16 + a]);
            float* op = out + ((size_t)b * SS + qrow0 + nt * 16 + a) * DD + h * HD;
            #pragma unroll
            for (int ft = 0; ft < 4; ++ft) {
                const int fb = ft * 16 + g * 4;
                float4 vv = {
                    (oacc[ft][nt][0] + Obuf[qq * 2112 + (fb + 0) * 33 + nt * 16 + a]) * inv,
                    (oacc[ft][nt][1] + Obuf[qq * 2112 + (fb + 1) * 33 + nt * 16 + a]) * inv,
                    (oacc[ft][nt][2] + Obuf[qq * 2112 + (fb + 2) * 33 + nt * 16 + a]) * inv,
                    (oacc[ft][nt][3] + Obuf[qq * 2112 + (fb + 3) * 33 + nt * 16 + a]) * inv };
                *(float4*)(op + fb) = vv;
            }
        }
    }
}

extern "C" void kernel_launch(void* const* d_in, const int* in_sizes, int n_in,
                              void* d_out, int out_size, void* d_ws, size_t ws_size,
                              hipStream_t stream) {
    const float* x  = (const float*)d_in[0];
    const float* wq = (const float*)d_in[1];
    float* out = (float*)d_out;
    unsigned short* q_h = (unsigned short*)d_ws;   // 8 MB

    dim3 ggrid(128, 8);
    gemm_kernel<<<ggrid, 256, 0, stream>>>(x, wq, q_h);
    attn_kernel<<<512, 512, 0, stream>>>((const __half*)q_h, out);
}

// Round 11
// 125.466 us; speedup vs baseline: 2.4424x; 2.4424x over previous
//
#include <hip/hip_runtime.h>
#include <hip/hip_fp16.h>
#include <math.h>

#define SS 2048
#define DD 512
#define NH 8
#define HD 64

typedef __attribute__((ext_vector_type(8))) short frag_ab;   // 8 fp16
typedef __attribute__((ext_vector_type(4))) float frag_cd;   // 4 fp32

static __device__ inline unsigned int pack_h2(float x, float y) {
    __half2 t = __floats2half2_rn(x, y);   // x -> low half
    return *(unsigned int*)&t;
}

// ---------- GEMM: q_h = fp16(x @ Wq); B transposed in-register during staging ----------
__global__ __launch_bounds__(256, 4) void gemm_kernel(const float* __restrict__ x,
                                                      const float* __restrict__ w,
                                                      unsigned short* __restrict__ q) {
    __shared__ __align__(16) unsigned short Ah[2][64 * 72];  // [m][k]
    __shared__ __align__(16) unsigned short Bt[2][64 * 72];  // [n][k]
    const int tid = threadIdx.x;
    const int lane = tid & 63, wv = tid >> 6;
    const int a = lane & 15, g = lane >> 4;
    const int bm = blockIdx.x, bn = blockIdx.y;

    frag_cd acc[4] = {};
    const int asr = tid >> 4;
    const int ac4 = (tid & 15) * 4;
    const int bnn = (tid & 31) * 2;
    const int bkk = (tid >> 5) * 8;

    float4 av[4];
    float2 bv[8];
    #pragma unroll
    for (int p = 0; p < 4; ++p)
        av[p] = *(const float4*)(x + (size_t)(bm * 64 + asr + p * 16) * 512 + ac4);
    #pragma unroll
    for (int j = 0; j < 8; ++j)
        bv[j] = *(const float2*)(w + (size_t)(bkk + j) * 512 + bn * 64 + bnn);

    for (int it = 0; it < 8; ++it) {
        const int cur = it & 1;
        #pragma unroll
        for (int p = 0; p < 4; ++p) {
            uint2 hh = { pack_h2(av[p].x, av[p].y), pack_h2(av[p].z, av[p].w) };
            *(uint2*)&Ah[cur][(asr + p * 16) * 72 + ac4] = hh;
        }
        {
            unsigned int t0[4], t1[4];
            #pragma unroll
            for (int j = 0; j < 4; ++j) {
                t0[j] = pack_h2(bv[2 * j].x, bv[2 * j + 1].x);
                t1[j] = pack_h2(bv[2 * j].y, bv[2 * j + 1].y);
            }
            *(uint4*)&Bt[cur][bnn * 72 + bkk]       = *(uint4*)t0;
            *(uint4*)&Bt[cur][(bnn + 1) * 72 + bkk] = *(uint4*)t1;
        }
        __syncthreads();
        if (it < 7) {
            const int k0 = (it + 1) * 64;
            #pragma unroll
            for (int p = 0; p < 4; ++p)
                av[p] = *(const float4*)(x + (size_t)(bm * 64 + asr + p * 16) * 512 + k0 + ac4);
            #pragma unroll
            for (int j = 0; j < 8; ++j)
                bv[j] = *(const float2*)(w + (size_t)(k0 + bkk + j) * 512 + bn * 64 + bnn);
        }
        #pragma unroll
        for (int kh = 0; kh < 2; ++kh) {
            const frag_ab bf = *(const frag_ab*)&Bt[cur][(wv * 16 + a) * 72 + kh * 32 + g * 8];
            #pragma unroll
            for (int mt = 0; mt < 4; ++mt) {
                const frag_ab af = *(const frag_ab*)&Ah[cur][(mt * 16 + a) * 72 + kh * 32 + g * 8];
                acc[mt] = __builtin_amdgcn_mfma_f32_16x16x32_f16(af, bf, acc[mt], 0, 0, 0);
            }
        }
    }
    #pragma unroll
    for (int mt = 0; mt < 4; ++mt)
        #pragma unroll
        for (int r = 0; r < 4; ++r) {
            const int m = bm * 64 + mt * 16 + g * 4 + r;
            const int n = bn * 64 + wv * 16 + a;
            __half hv = __float2half_rn(acc[mt][r]);
            q[(size_t)m * 512 + n] = *(unsigned short*)&hv;
        }
}

// ---------- Flash attention: 8 waves = 4 q-quarters x 2 key-halves; in-block combine ----
// R9 structure (P staged through per-wave LDS, 64 VGPR, no spill) with the verified
// fixes only: Vt uses the R10 stride-64 XOR-swizzled layout (floor-rate transposed
// writes; R9's stride-72 V-writes were 8-way conflicted), and the exp2 offset is
// folded into the MFMA C-init. Kt/Pq stride 72 (floor-rate per bank audit).
__global__ __launch_bounds__(512, 4) void attn_kernel(const __half* __restrict__ qg,
                                                      float* __restrict__ out) {
    __shared__ __align__(16) unsigned short Kt[2][64 * 72];   // [kv][key][f]     18.4 KB
    __shared__ __align__(16) unsigned short Vt[2][64 * 64];   // [kv][f][key] swz 16 KB
    __shared__ __align__(16) unsigned short Pq[8][32 * 72];   // per-wave [q][key] 36.9 KB

    const int tid = threadIdx.x;
    const int lane = tid & 63, wv = tid >> 6;
    const int a = lane & 15, g = lane >> 4;
    const int a7 = a & 7;
    const int qq = wv & 3;            // q quarter (32 q)
    const int kv = wv >> 2;           // key half (1024 keys)
    const int bid = blockIdx.x;       // 512 = 16(qt) * 8(h) * 4(b)
    const int qt = bid & 15;
    const int h  = (bid >> 4) & 7;
    const int b  = bid >> 7;

    const unsigned short* qbh = (const unsigned short*)qg + (size_t)b * SS * DD + h * HD;
    const int qrow0 = qt * 128 + qq * 32;

    // Q B-fragments, pre-scaled by 0.125*log2(e)
    frag_ab qf[2][2];
    const __half2 qsc = __float2half2_rn(0.18033688011112042f);
    #pragma unroll
    for (int nt = 0; nt < 2; ++nt)
        #pragma unroll
        for (int kh = 0; kh < 2; ++kh) {
            frag_ab t = *(const frag_ab*)(qbh + (size_t)(qrow0 + nt * 16 + a) * DD + kh * 32 + g * 8);
            __half2* ph = (__half2*)&t;
            #pragma unroll
            for (int i = 0; i < 4; ++i) ph[i] = __hmul2(ph[i], qsc);
            qf[nt][kh] = t;
        }

    frag_cd oacc[4][2] = {};          // [ft][nt]
    float lsum[2] = {0.f, 0.f};

    // staging: threads 0-255 stage key-half 0, 256-511 half 1 (== own wave's kv)
    const int t8 = tid & 255;
    const int f0 = (t8 & 31) * 2;     // feature column (even)
    const int u8 = t8 >> 5;           // key chunk 0..7
    const int r0 = u8 * 8;
    const int keybase = (tid >> 8) * 1024;
    unsigned short* Ks = Kt[tid >> 8];
    unsigned short* Vs = Vt[tid >> 8];
    unsigned short* myP = Pq[wv];

    unsigned int d[8];
    #pragma unroll
    for (int k = 0; k < 8; ++k)
        d[k] = *(const unsigned int*)(qbh + (size_t)(keybase + r0 + k) * DD + f0);

    const unsigned short* Kc = Kt[kv];
    const unsigned short* Vc = Vt[kv];
    const float coff = -11.541560327111707f;   // -8*log2(e): p = 2^(s' + coff) = e^(s-8)

    for (int it = 0; it < 16; ++it) {
        __syncthreads();              // all waves done reading previous tiles
        #pragma unroll
        for (int k = 0; k < 8; ++k)   // K key-major, stride 72 (floor-rate)
            *(unsigned int*)&Ks[(r0 + k) * 72 + f0] = d[k];
        {                             // V^T feature-major, stride 64 + XOR swizzle
            unsigned int vlo[4], vhi[4];
            #pragma unroll
            for (int j = 0; j < 4; ++j) {
                vlo[j] = (d[2 * j] & 0xFFFFu) | (d[2 * j + 1] << 16);
                vhi[j] = (d[2 * j] >> 16)     | (d[2 * j + 1] & 0xFFFF0000u);
            }
            *(uint4*)&Vs[f0 * 64 + ((u8 ^ (f0 & 7)) << 3)]             = *(uint4*)vlo;
            *(uint4*)&Vs[(f0 + 1) * 64 + ((u8 ^ ((f0 + 1) & 7)) << 3)] = *(uint4*)vhi;
        }
        __syncthreads();              // staged tiles visible

        if (it + 1 < 16) {            // prefetch next tile (overlaps compute)
            const int kb = keybase + (it + 1) * 64;
            #pragma unroll
            for (int k = 0; k < 8; ++k)
                d[k] = *(const unsigned int*)(qbh + (size_t)(kb + r0 + k) * DD + f0);
        }

        // ---- S^T = K . Q^T (C-init = exp offset), exp2, stage P ----
        #pragma unroll
        for (int kt = 0; kt < 4; ++kt) {
            const frag_ab ka0 = *(const frag_ab*)&Kc[(kt * 16 + a) * 72 + g * 8];
            const frag_ab ka1 = *(const frag_ab*)&Kc[(kt * 16 + a) * 72 + 32 + g * 8];
            #pragma unroll
            for (int nt = 0; nt < 2; ++nt) {
                frag_cd c = {coff, coff, coff, coff};
                c = __builtin_amdgcn_mfma_f32_16x16x32_f16(ka0, qf[nt][0], c, 0, 0, 0);
                c = __builtin_amdgcn_mfma_f32_16x16x32_f16(ka1, qf[nt][1], c, 0, 0, 0);
                const float p0 = __builtin_amdgcn_exp2f(c[0]);
                const float p1 = __builtin_amdgcn_exp2f(c[1]);
                const float p2 = __builtin_amdgcn_exp2f(c[2]);
                const float p3 = __builtin_amdgcn_exp2f(c[3]);
                lsum[nt] += (p0 + p1) + (p2 + p3);
                uint2 pw = { pack_h2(p0, p1), pack_h2(p2, p3) };
                *(uint2*)&myP[(nt * 16 + a) * 72 + kt * 16 + g * 4] = pw;  // wave-private
            }
        }
        // ---- O^T += V^T . P^T ----
        #pragma unroll
        for (int kh = 0; kh < 2; ++kh) {
            frag_ab va[4], pb[2];
            #pragma unroll
            for (int ft = 0; ft < 4; ++ft)
                va[ft] = *(const frag_ab*)&Vc[(ft * 16 + a) * 64 + (((4 * kh + g) ^ a7) << 3)];
            #pragma unroll
            for (int nt = 0; nt < 2; ++nt)
                pb[nt] = *(const frag_ab*)&myP[(nt * 16 + a) * 72 + kh * 32 + g * 8];
            #pragma unroll
            for (int ft = 0; ft < 4; ++ft)
                #pragma unroll
                for (int nt = 0; nt < 2; ++nt)
                    oacc[ft][nt] = __builtin_amdgcn_mfma_f32_16x16x32_f16(va[ft], pb[nt], oacc[ft][nt], 0, 0, 0);
        }
    }

    // ---- in-block combine: kv=1 -> LDS; kv=0 adds, normalizes, writes ----
    #pragma unroll
    for (int nt = 0; nt < 2; ++nt) {
        lsum[nt] += __shfl_xor(lsum[nt], 16, 64);
        lsum[nt] += __shfl_xor(lsum[nt], 32, 64);
    }
    __syncthreads();                              // all tile/P reads done; LDS reusable
    float* Obuf = (float*)&Pq[0][0];              // [qq][f 64][q 32+1 pad] = 33.8 KB
    float* Lbuf = (float*)&Kt[0][0];              // [qq][q 32]
    if (kv == 1) {
        #pragma unroll
        for (int ft = 0; ft < 4; ++ft)
            #pragma unroll
            for (int nt = 0; nt < 2; ++nt)
                #pragma unroll
                for (int r = 0; r < 4; ++r)
                    Obuf[qq * 2112 + (ft * 16 + g * 4 + r) * 33 + nt * 16 + a] = oacc[ft][nt][r];
        if (g == 0)
            #pragma unroll
            for (int nt = 0; nt < 2; ++nt)
                Lbuf[qq * 32 + nt * 16 + a] = lsum[nt];
    }
    __syncthreads();
    if (kv == 0) {
        #pragma unroll
        for (int nt = 0; nt < 2; ++nt) {
            const float inv = 1.f / (lsum[nt] + Lbuf[qq * 32 + nt * 16 + a]);
            float* op = out + ((size_t)b * SS + qrow0 + nt * 16 + a) * DD + h * HD;
            #pragma unroll
            for (int ft = 0; ft < 4; ++ft) {
                const int fb = ft * 16 + g * 4;
                float4 vv = {
                    (oacc[ft][nt][0] + Obuf[qq * 2112 + (fb + 0) * 33 + nt * 16 + a]) * inv,
                    (oacc[ft][nt][1] + Obuf[qq * 2112 + (fb + 1) * 33 + nt * 16 + a]) * inv,
                    (oacc[ft][nt][2] + Obuf[qq * 2112 + (fb + 2) * 33 + nt * 16 + a]) * inv,
                    (oacc[ft][nt][3] + Obuf[qq * 2112 + (fb + 3) * 33 + nt * 16 + a]) * inv };
                *(float4*)(op + fb) = vv;
            }
        }
    }
}

extern "C" void kernel_launch(void* const* d_in, const int* in_sizes, int n_in,
                              void* d_out, int out_size, void* d_ws, size_t ws_size,
                              hipStream_t stream) {
    const float* x  = (const float*)d_in[0];
    const float* wq = (const float*)d_in[1];
    float* out = (float*)d_out;
    unsigned short* q_h = (unsigned short*)d_ws;   // 8 MB

    dim3 ggrid(128, 8);
    gemm_kernel<<<ggrid, 256, 0, stream>>>(x, wq, q_h);
    attn_kernel<<<512, 512, 0, stream>>>((const __half*)q_h, out);
}